// Round 1
// baseline (212.006 us; speedup 1.0000x reference)
//
#include <hip/hip_runtime.h>
#include <hip/hip_bf16.h>
#include <math.h>

// Problem constants
#define B 1024
#define C 512
#define S 32
#define E 128

// ---------------------------------------------------------------------------
// Workspace layout (floats):
//   xn     : [B][E]          @ 0          (131072)
//   Wn     : [C][S][E]       @ 131072     (2097152)
//   G      : [C][S][S]       @ 2228224    (524288)
//   logits : [B][C]          @ 2752512    (524288)
//   loss   : [B]             @ 3276800    (1024)
// total ~13.1 MB
// ---------------------------------------------------------------------------
#define OFF_XN     0
#define OFF_WN     131072
#define OFF_G      2228224
#define OFF_LOGITS 2752512
#define OFF_LOSS   3276800

// Normalize x rows: one wave per row, 2 elems/thread
__global__ void k_norm_x(const float* __restrict__ x, float* __restrict__ xn) {
    int b = blockIdx.x;
    int t = threadIdx.x;  // 64
    float2 v = reinterpret_cast<const float2*>(x + (size_t)b * E)[t];
    float ss = v.x * v.x + v.y * v.y;
    #pragma unroll
    for (int off = 32; off; off >>= 1) ss += __shfl_xor(ss, off);
    float scale = 1.0f / fmaxf(sqrtf(ss), 1e-12f);
    float2 o; o.x = v.x * scale; o.y = v.y * scale;
    reinterpret_cast<float2*>(xn + (size_t)b * E)[t] = o;
}

// Per class c: normalize the S rows of W[c], write Wn, compute Gram G[c]=Wn Wn^T
__global__ void k_norm_w_gram(const float* __restrict__ W,
                              float* __restrict__ Wn,
                              float* __restrict__ G) {
    __shared__ float sw[S][132];  // padded: stride 132 floats (float4-aligned)
    int c = blockIdx.x, t = threadIdx.x;  // 256 threads
    const float4* src = reinterpret_cast<const float4*>(W + (size_t)c * S * E);
    for (int i = t; i < 1024; i += 256)
        *reinterpret_cast<float4*>(&sw[i >> 5][(i & 31) << 2]) = src[i];
    __syncthreads();
    // row sum-of-squares: 8 threads per row
    int r = t >> 3, j = t & 7;
    float ss = 0.f;
    #pragma unroll
    for (int k = 0; k < E; k += 8) { float v = sw[r][k + j]; ss += v * v; }
    #pragma unroll
    for (int m = 4; m; m >>= 1) ss += __shfl_xor(ss, m, 8);
    float scale = 1.0f / fmaxf(sqrtf(ss), 1e-12f);
    #pragma unroll
    for (int k = 0; k < E; k += 8) sw[r][k + j] *= scale;
    __syncthreads();
    float4* wn4 = reinterpret_cast<float4*>(Wn + (size_t)c * S * E);
    for (int i = t; i < 1024; i += 256)
        wn4[i] = *reinterpret_cast<const float4*>(&sw[i >> 5][(i & 31) << 2]);
    // Gram: 4 entries per thread
    float* g = G + (size_t)c * S * S;
    for (int idx = t; idx < 1024; idx += 256) {
        int a = idx >> 5, bb = idx & 31;
        float acc = 0.f;
        #pragma unroll 4
        for (int k = 0; k < E; ++k) acc += sw[a][k] * sw[bb][k];
        g[idx] = acc;
    }
}

// Fused logits: block = (b-tile of 64, one class c).
// coef = xn_tile · Wn[c]^T  (64x32, K=128) via register tiling (4b x 2s per thread)
// then logit = |coef|^2 / max(sqrt(coef^T G coef), 1e-12)
__global__ __launch_bounds__(256) void k_logits(const float* __restrict__ xn,
                                                const float* __restrict__ Wn,
                                                const float* __restrict__ G,
                                                float* __restrict__ logits) {
    __shared__ float sW[S][132];   // Wn[c], padded
    __shared__ float sG[S][33];    // Gram
    __shared__ float sX[64][132];  // xn tile, padded
    __shared__ float sC[64][33];   // coef tile

    int tid = threadIdx.x;            // 256
    int c = blockIdx.y;
    int b0 = blockIdx.x * 64;

    const float4* wn4 = reinterpret_cast<const float4*>(Wn + (size_t)c * S * E);
    for (int i = tid; i < 1024; i += 256)
        *reinterpret_cast<float4*>(&sW[i >> 5][(i & 31) << 2]) = wn4[i];
    const float4* x4 = reinterpret_cast<const float4*>(xn + (size_t)b0 * E);
    for (int i = tid; i < 2048; i += 256)
        *reinterpret_cast<float4*>(&sX[i >> 5][(i & 31) << 2]) = x4[i];
    const float* g = G + (size_t)c * S * S;
    for (int i = tid; i < 1024; i += 256) sG[i >> 5][i & 31] = g[i];
    __syncthreads();

    // ---- GEMM1: coef tile ----
    int tx = tid & 15, ty = tid >> 4;      // tx -> s-pair, ty -> b-quad
    int s0 = tx * 2, bl0 = ty * 4;
    float acc[4][2] = {{0.f, 0.f}, {0.f, 0.f}, {0.f, 0.f}, {0.f, 0.f}};
    #pragma unroll 8
    for (int k = 0; k < E; k += 4) {
        float4 w0 = *reinterpret_cast<const float4*>(&sW[s0][k]);
        float4 w1 = *reinterpret_cast<const float4*>(&sW[s0 + 1][k]);
        #pragma unroll
        for (int i = 0; i < 4; ++i) {
            float4 xv = *reinterpret_cast<const float4*>(&sX[bl0 + i][k]);
            acc[i][0] += xv.x * w0.x + xv.y * w0.y + xv.z * w0.z + xv.w * w0.w;
            acc[i][1] += xv.x * w1.x + xv.y * w1.y + xv.z * w1.z + xv.w * w1.w;
        }
    }
    #pragma unroll
    for (int i = 0; i < 4; ++i) {
        sC[bl0 + i][s0]     = acc[i][0];
        sC[bl0 + i][s0 + 1] = acc[i][1];
    }
    __syncthreads();

    // ---- quadratic form: 4 threads per b-row ----
    int bl = tid >> 2, part = tid & 3;
    float c32[S];
    #pragma unroll
    for (int s = 0; s < S; ++s) c32[s] = sC[bl][s];
    float num = 0.f, psq = 0.f;
    #pragma unroll
    for (int i = 0; i < 8; ++i) {
        int srow = part * 8 + i;
        float cs = c32[srow];
        num += cs * cs;
        float dot = 0.f;
        #pragma unroll
        for (int sp = 0; sp < S; ++sp) dot += sG[srow][sp] * c32[sp];
        psq += cs * dot;
    }
    psq += __shfl_xor(psq, 1); psq += __shfl_xor(psq, 2);
    num += __shfl_xor(num, 1); num += __shfl_xor(num, 2);
    if (part == 0) {
        float logit = num / fmaxf(sqrtf(psq), 1e-12f);
        logits[(size_t)(b0 + bl) * C + c] = logit;
    }
}

// Per-row log-softmax + pick label: loss[b] = lse(s*logit) - sum_c y*s*logit
__global__ void k_loss(const float* __restrict__ logits,
                       const float* __restrict__ y,
                       const float* __restrict__ s_ptr,
                       float* __restrict__ loss) {
    int b = blockIdx.x, t = threadIdx.x;  // 128 threads
    float s = s_ptr[0];
    float4 l4 = reinterpret_cast<const float4*>(logits + (size_t)b * C)[t];
    float4 y4 = reinterpret_cast<const float4*>(y + (size_t)b * C)[t];
    float z0 = l4.x * s, z1 = l4.y * s, z2 = l4.z * s, z3 = l4.w * s;
    float m = fmaxf(fmaxf(z0, z1), fmaxf(z2, z3));
    #pragma unroll
    for (int off = 32; off; off >>= 1) m = fmaxf(m, __shfl_xor(m, off));
    __shared__ float redm[2];
    if ((t & 63) == 0) redm[t >> 6] = m;
    __syncthreads();
    m = fmaxf(redm[0], redm[1]);
    float se = expf(z0 - m) + expf(z1 - m) + expf(z2 - m) + expf(z3 - m);
    float yz = y4.x * z0 + y4.y * z1 + y4.z * z2 + y4.w * z3;
    #pragma unroll
    for (int off = 32; off; off >>= 1) {
        se += __shfl_xor(se, off);
        yz += __shfl_xor(yz, off);
    }
    __shared__ float red2[4];
    if ((t & 63) == 0) { red2[t >> 6] = se; red2[2 + (t >> 6)] = yz; }
    __syncthreads();
    if (t == 0) loss[b] = m + logf(red2[0] + red2[1]) - (red2[2] + red2[3]);
}

__global__ void k_reduce(const float* __restrict__ loss, float* __restrict__ out) {
    int t = threadIdx.x;  // 256
    float v = loss[t] + loss[t + 256] + loss[t + 512] + loss[t + 768];
    #pragma unroll
    for (int off = 32; off; off >>= 1) v += __shfl_xor(v, off);
    __shared__ float r[4];
    if ((t & 63) == 0) r[t >> 6] = v;
    __syncthreads();
    if (t == 0) out[0] = (r[0] + r[1] + r[2] + r[3]) * (1.0f / (float)B);
}

extern "C" void kernel_launch(void* const* d_in, const int* in_sizes, int n_in,
                              void* d_out, int out_size, void* d_ws, size_t ws_size,
                              hipStream_t stream) {
    const float* x = (const float*)d_in[0];
    const float* y = (const float*)d_in[1];
    const float* W = (const float*)d_in[2];
    const float* s = (const float*)d_in[3];
    float* ws = (float*)d_ws;
    float* out = (float*)d_out;

    float* xn     = ws + OFF_XN;
    float* Wn     = ws + OFF_WN;
    float* G      = ws + OFF_G;
    float* logits = ws + OFF_LOGITS;
    float* loss   = ws + OFF_LOSS;

    k_norm_x<<<B, 64, 0, stream>>>(x, xn);
    k_norm_w_gram<<<C, 256, 0, stream>>>(W, Wn, G);
    k_logits<<<dim3(B / 64, C), 256, 0, stream>>>(xn, Wn, G, logits);
    k_loss<<<B, 128, 0, stream>>>(logits, y, s, loss);
    k_reduce<<<1, 256, 0, stream>>>(loss, out);
}

// Round 2
// 61.996 us; speedup vs baseline: 3.4197x; 3.4197x over previous
//
#include <hip/hip_runtime.h>
#include <math.h>

#define B 1024
#define C 512
#define S 32
#define E 128

typedef __attribute__((ext_vector_type(8))) short bf16x8;
typedef __attribute__((ext_vector_type(4))) float f32x4;

// ---------------------------------------------------------------------------
// Workspace layout (float units):
//   xfrag  : bf16 [B/16][4 kt][64 lane][8 j]   = 131072 bf16  @ f0        (65536 f)
//   wfrag  : bf16 [C][4 kt][2 mt][64][8]       = 2097152 bf16 @ f65536    (1048576 f)
//   gfrag  : bf16 [C][2 mt][64][8]             = 524288 bf16  @ f1114112  (262144 f)
//   logits : f32 [B][C]                        @ f1376256  (524288 f)
//   loss   : f32 [B]                           @ f1900544
// Fragment element mapping (mfma_f32_16x16x32_bf16 A/B operand, derived from
// m156/m162 tr-read layout): frag[j] = M[row = lane&15][k = 4*(lane>>4) + (j&3) + 16*(j>>2)]
// ---------------------------------------------------------------------------
#define OFF_XFRAG  0
#define OFF_WFRAG  65536
#define OFF_GFRAG  1114112
#define OFF_LOGITS 1376256
#define OFF_LOSS   1900544

__device__ inline unsigned short f2bf(float f) {
    unsigned u = __float_as_uint(f);
    return (unsigned short)((u + 0x7fffu + ((u >> 16) & 1u)) >> 16);
}

// Normalize 16 rows of x, emit bf16 B-operand fragments (pre-swizzled).
__global__ __launch_bounds__(256) void k_prep_x(const float* __restrict__ x,
                                                unsigned short* __restrict__ xfrag) {
    __shared__ float sX[16][128];
    int t = threadIdx.x, bt = blockIdx.x;
    const float4* gx = reinterpret_cast<const float4*>(x + (size_t)bt * 16 * 128);
    float4* s4 = reinterpret_cast<float4*>(&sX[0][0]);
    s4[t] = gx[t];
    s4[t + 256] = gx[t + 256];
    __syncthreads();
    int r = t >> 4, j = t & 15;
    float ss = 0.f;
    #pragma unroll
    for (int i = 0; i < 8; ++i) { float v = sX[r][j + 16 * i]; ss += v * v; }
    #pragma unroll
    for (int m = 1; m < 16; m <<= 1) ss += __shfl_xor(ss, m, 16);
    float sc = 1.0f / fmaxf(sqrtf(ss), 1e-12f);
    #pragma unroll
    for (int i = 0; i < 8; ++i) sX[r][j + 16 * i] *= sc;
    __syncthreads();
    // pack: 256 chunks of 8 bf16 (16B); chunk t = (kt, lane)
    int kt = t >> 6, lane = t & 63;
    int row = lane & 15;
    union { unsigned short u[8]; int4 v; } pk;
    #pragma unroll
    for (int jj = 0; jj < 8; ++jj) {
        int k = kt * 32 + 4 * (lane >> 4) + (jj & 3) + 16 * (jj >> 2);
        pk.u[jj] = f2bf(sX[row][k]);
    }
    reinterpret_cast<int4*>(xfrag + (size_t)bt * 2048)[t] = pk.v;
}

// Per class: normalize W rows, emit Wn A-fragments (bf16) + Gram A-fragments (bf16).
__global__ __launch_bounds__(256) void k_prep_w(const float* __restrict__ W,
                                                unsigned short* __restrict__ wfrag,
                                                unsigned short* __restrict__ gfrag) {
    __shared__ float sW[32][128];
    __shared__ float sG[32][33];
    int t = threadIdx.x, c = blockIdx.x;
    const float4* gw = reinterpret_cast<const float4*>(W + (size_t)c * S * E);
    float4* s4 = reinterpret_cast<float4*>(&sW[0][0]);
    #pragma unroll
    for (int i = 0; i < 4; ++i) s4[t + 256 * i] = gw[t + 256 * i];
    __syncthreads();
    int r = t >> 3, j = t & 7;
    float ss = 0.f;
    #pragma unroll
    for (int i = 0; i < 16; ++i) { float v = sW[r][j + 8 * i]; ss += v * v; }
    #pragma unroll
    for (int m = 1; m < 8; m <<= 1) ss += __shfl_xor(ss, m, 8);
    float sc = 1.0f / fmaxf(sqrtf(ss), 1e-12f);
    #pragma unroll
    for (int i = 0; i < 16; ++i) sW[r][j + 8 * i] *= sc;
    __syncthreads();
    // Gram (fp32 in LDS): 4 entries/thread
    #pragma unroll
    for (int i = 0; i < 4; ++i) {
        int e = t * 4 + i; int a = e >> 5, bb = e & 31;
        const float4* va = reinterpret_cast<const float4*>(&sW[a][0]);
        const float4* vb = reinterpret_cast<const float4*>(&sW[bb][0]);
        float acc = 0.f;
        #pragma unroll
        for (int k = 0; k < 32; ++k) {
            float4 A = va[k], Bv = vb[k];
            acc += A.x * Bv.x + A.y * Bv.y + A.z * Bv.z + A.w * Bv.w;
        }
        sG[a][bb] = acc;
    }
    __syncthreads();
    // Wn fragments: 512 chunks; chunk ci = (kt, mt, lane)
    for (int ci = t; ci < 512; ci += 256) {
        int kt = ci >> 7, mt = (ci >> 6) & 1, lane = ci & 63;
        int s = mt * 16 + (lane & 15);
        union { unsigned short u[8]; int4 v; } pk;
        #pragma unroll
        for (int jj = 0; jj < 8; ++jj) {
            int k = kt * 32 + 4 * (lane >> 4) + (jj & 3) + 16 * (jj >> 2);
            pk.u[jj] = f2bf(sW[s][k]);
        }
        reinterpret_cast<int4*>(wfrag + (size_t)c * 4096)[ci] = pk.v;
    }
    // G fragments: 128 chunks; chunk t = (mt, lane)
    if (t < 128) {
        int mt = t >> 6, lane = t & 63;
        int s = mt * 16 + (lane & 15);
        union { unsigned short u[8]; int4 v; } pk;
        #pragma unroll
        for (int jj = 0; jj < 8; ++jj) {
            int k = 4 * (lane >> 4) + (jj & 3) + 16 * (jj >> 2);
            pk.u[jj] = f2bf(sG[s][k]);
        }
        reinterpret_cast<int4*>(gfrag + (size_t)c * 1024)[t] = pk.v;
    }
}

// Fused logits: block = 32 b-rows x 4 classes (one wave per class).
// GEMM1 (MFMA): coef[s][b] = Wn[c] . xn^T   (M=s=32 -> 2 mt, N=b=32 -> 2 nt, K=128 -> 4 kt)
// GEMM2 (MFMA): H = G . coef (coef acc feeds B operand with a pure per-lane bf16 pack)
// logit = |coef|^2 / max(sqrt(coef.H), 1e-12)
__global__ __launch_bounds__(256) void k_logits_mfma(const unsigned short* __restrict__ xfrag,
                                                     const unsigned short* __restrict__ wfrag,
                                                     const unsigned short* __restrict__ gfrag,
                                                     float* __restrict__ logits) {
    __shared__ int4 smem[3072];  // 48KB: X [0,512) | W [512,2560) | G [2560,3072)
    int t = threadIdx.x;
    int w = t >> 6, lane = t & 63;
    int b0 = blockIdx.x * 32;
    int c0 = blockIdx.y * 4;

    const int4* gX = reinterpret_cast<const int4*>(xfrag) + (size_t)(b0 >> 4) * 256;
    const int4* gW = reinterpret_cast<const int4*>(wfrag) + (size_t)c0 * 512;
    const int4* gG = reinterpret_cast<const int4*>(gfrag) + (size_t)c0 * 128;
    #pragma unroll
    for (int i = 0; i < 2; ++i) smem[t + 256 * i] = gX[t + 256 * i];
    #pragma unroll
    for (int i = 0; i < 8; ++i) smem[512 + t + 256 * i] = gW[t + 256 * i];
    #pragma unroll
    for (int i = 0; i < 2; ++i) smem[2560 + t + 256 * i] = gG[t + 256 * i];
    __syncthreads();

    const bf16x8* fr = reinterpret_cast<const bf16x8*>(smem);
    f32x4 acc00 = {0.f, 0.f, 0.f, 0.f}, acc01 = acc00, acc10 = acc00, acc11 = acc00;
    #pragma unroll
    for (int kt = 0; kt < 4; ++kt) {
        bf16x8 a0  = fr[512 + (w * 8 + kt * 2 + 0) * 64 + lane];
        bf16x8 a1  = fr[512 + (w * 8 + kt * 2 + 1) * 64 + lane];
        bf16x8 bv0 = fr[(0 * 4 + kt) * 64 + lane];
        bf16x8 bv1 = fr[(1 * 4 + kt) * 64 + lane];
        acc00 = __builtin_amdgcn_mfma_f32_16x16x32_bf16(a0, bv0, acc00, 0, 0, 0);
        acc01 = __builtin_amdgcn_mfma_f32_16x16x32_bf16(a0, bv1, acc01, 0, 0, 0);
        acc10 = __builtin_amdgcn_mfma_f32_16x16x32_bf16(a1, bv0, acc10, 0, 0, 0);
        acc11 = __builtin_amdgcn_mfma_f32_16x16x32_bf16(a1, bv1, acc11, 0, 0, 0);
    }

    // coef -> bf16 B-fragments (D layout == B layout, per-lane pack, no shuffles)
    union { unsigned short u[8]; bf16x8 v; } p0, p1;
    #pragma unroll
    for (int r = 0; r < 4; ++r) {
        p0.u[r]     = f2bf(acc00[r]);
        p0.u[r + 4] = f2bf(acc10[r]);
        p1.u[r]     = f2bf(acc01[r]);
        p1.u[r + 4] = f2bf(acc11[r]);
    }
    bf16x8 g0 = fr[2560 + (w * 2 + 0) * 64 + lane];
    bf16x8 g1 = fr[2560 + (w * 2 + 1) * 64 + lane];
    f32x4 h00 = {0.f, 0.f, 0.f, 0.f}, h01 = h00, h10 = h00, h11 = h00;
    h00 = __builtin_amdgcn_mfma_f32_16x16x32_bf16(g0, p0.v, h00, 0, 0, 0);
    h01 = __builtin_amdgcn_mfma_f32_16x16x32_bf16(g0, p1.v, h01, 0, 0, 0);
    h10 = __builtin_amdgcn_mfma_f32_16x16x32_bf16(g1, p0.v, h10, 0, 0, 0);
    h11 = __builtin_amdgcn_mfma_f32_16x16x32_bf16(g1, p1.v, h11, 0, 0, 0);

    // num / psq per b (lane&15 within nt group), reduce across lane>>4 groups
    float n0 = 0.f, q0 = 0.f, n1 = 0.f, q1 = 0.f;
    #pragma unroll
    for (int r = 0; r < 4; ++r) {
        n0 += acc00[r] * acc00[r] + acc10[r] * acc10[r];
        q0 += acc00[r] * h00[r]   + acc10[r] * h10[r];
        n1 += acc01[r] * acc01[r] + acc11[r] * acc11[r];
        q1 += acc01[r] * h01[r]   + acc11[r] * h11[r];
    }
    n0 += __shfl_xor(n0, 16); n0 += __shfl_xor(n0, 32);
    q0 += __shfl_xor(q0, 16); q0 += __shfl_xor(q0, 32);
    n1 += __shfl_xor(n1, 16); n1 += __shfl_xor(n1, 32);
    q1 += __shfl_xor(q1, 16); q1 += __shfl_xor(q1, 32);
    if (lane < 16) {
        int c = c0 + w;
        logits[(size_t)(b0 + lane) * C + c]      = n0 / fmaxf(sqrtf(q0), 1e-12f);
        logits[(size_t)(b0 + 16 + lane) * C + c] = n1 / fmaxf(sqrtf(q1), 1e-12f);
    }
}

// Per-row log-softmax + label pick
__global__ void k_loss(const float* __restrict__ logits,
                       const float* __restrict__ y,
                       const float* __restrict__ s_ptr,
                       float* __restrict__ loss) {
    int b = blockIdx.x, t = threadIdx.x;  // 128 threads
    float s = s_ptr[0];
    float4 l4 = reinterpret_cast<const float4*>(logits + (size_t)b * C)[t];
    float4 y4 = reinterpret_cast<const float4*>(y + (size_t)b * C)[t];
    float z0 = l4.x * s, z1 = l4.y * s, z2 = l4.z * s, z3 = l4.w * s;
    float m = fmaxf(fmaxf(z0, z1), fmaxf(z2, z3));
    #pragma unroll
    for (int off = 32; off; off >>= 1) m = fmaxf(m, __shfl_xor(m, off));
    __shared__ float redm[2];
    if ((t & 63) == 0) redm[t >> 6] = m;
    __syncthreads();
    m = fmaxf(redm[0], redm[1]);
    float se = expf(z0 - m) + expf(z1 - m) + expf(z2 - m) + expf(z3 - m);
    float yz = y4.x * z0 + y4.y * z1 + y4.z * z2 + y4.w * z3;
    #pragma unroll
    for (int off = 32; off; off >>= 1) {
        se += __shfl_xor(se, off);
        yz += __shfl_xor(yz, off);
    }
    __shared__ float red2[4];
    if ((t & 63) == 0) { red2[t >> 6] = se; red2[2 + (t >> 6)] = yz; }
    __syncthreads();
    if (t == 0) loss[b] = m + logf(red2[0] + red2[1]) - (red2[2] + red2[3]);
}

__global__ void k_reduce(const float* __restrict__ loss, float* __restrict__ out) {
    int t = threadIdx.x;  // 256
    float v = loss[t] + loss[t + 256] + loss[t + 512] + loss[t + 768];
    #pragma unroll
    for (int off = 32; off; off >>= 1) v += __shfl_xor(v, off);
    __shared__ float r[4];
    if ((t & 63) == 0) r[t >> 6] = v;
    __syncthreads();
    if (t == 0) out[0] = (r[0] + r[1] + r[2] + r[3]) * (1.0f / (float)B);
}

extern "C" void kernel_launch(void* const* d_in, const int* in_sizes, int n_in,
                              void* d_out, int out_size, void* d_ws, size_t ws_size,
                              hipStream_t stream) {
    const float* x = (const float*)d_in[0];
    const float* y = (const float*)d_in[1];
    const float* W = (const float*)d_in[2];
    const float* s = (const float*)d_in[3];
    float* ws = (float*)d_ws;
    float* out = (float*)d_out;

    unsigned short* xfrag = (unsigned short*)(ws + OFF_XFRAG);
    unsigned short* wfrag = (unsigned short*)(ws + OFF_WFRAG);
    unsigned short* gfrag = (unsigned short*)(ws + OFF_GFRAG);
    float* logits = ws + OFF_LOGITS;
    float* loss   = ws + OFF_LOSS;

    k_prep_x<<<B / 16, 256, 0, stream>>>(x, xfrag);
    k_prep_w<<<C, 256, 0, stream>>>(W, wfrag, gfrag);
    k_logits_mfma<<<dim3(B / 32, C / 4), 256, 0, stream>>>(xfrag, wfrag, gfrag, logits);
    k_loss<<<B, 128, 0, stream>>>(logits, y, s, loss);
    k_reduce<<<1, 256, 0, stream>>>(loss, out);
}

// Round 3
// 32.369 us; speedup vs baseline: 6.5497x; 1.9153x over previous
//
#include <hip/hip_runtime.h>
#include <math.h>

#define B 1024
#define C 512
#define S 32
#define E 128

typedef __attribute__((ext_vector_type(8))) short bf16x8;
typedef __attribute__((ext_vector_type(4))) float f32x4;

// ---------------------------------------------------------------------------
// Workspace layout (float units):
//   xfrag  : bf16 [B/16][4 kt][64 lane][8 j]   @ f0        (65536 f)
//   wfrag  : bf16 [C][4 kt][2 mt][64][8]       @ f65536    (1048576 f)
//   gfrag  : bf16 [C][2 mt][64][8]             @ f1114112  (262144 f)
//   logits : f32 [B][C]                        @ f1376256  (524288 f)
//   loss   : f32 [B]                           @ f1900544
// Fragment mapping (mfma_f32_16x16x32_bf16 A/B operand):
//   frag[j] = M[row = lane&15][k = 4*(lane>>4) + (j&3) + 16*(j>>2)]
// D mapping: D[row = 4*(lane>>4)+r][col = lane&15]
// ---------------------------------------------------------------------------
#define OFF_XFRAG  0
#define OFF_WFRAG  65536
#define OFF_GFRAG  1114112
#define OFF_LOGITS 1376256
#define OFF_LOSS   1900544

__device__ inline unsigned short f2bf(float f) {
    unsigned u = __float_as_uint(f);
    return (unsigned short)((u + 0x7fffu + ((u >> 16) & 1u)) >> 16);
}

// Fused prep: blocks [0,64) = x rows (16 each); blocks [64,576) = one class each.
// W path: normalize rows -> pack wfrag -> Gram via MFMA (A-frag == B-frag for
// symmetric product) -> pack gfrag per-lane via G symmetry.
__global__ __launch_bounds__(256) void k_prep(const float* __restrict__ x,
                                              const float* __restrict__ W,
                                              unsigned short* __restrict__ xfrag,
                                              unsigned short* __restrict__ wfrag,
                                              unsigned short* __restrict__ gfrag) {
    __shared__ float sM[32][128];
    __shared__ int4 wf[512];
    int t = threadIdx.x;
    int blk = blockIdx.x;
    if (blk < 64) {
        const float4* gx = reinterpret_cast<const float4*>(x + (size_t)blk * 16 * 128);
        float4* s4 = reinterpret_cast<float4*>(&sM[0][0]);
        s4[t] = gx[t];
        s4[t + 256] = gx[t + 256];
        __syncthreads();
        int r = t >> 4, j = t & 15;
        float ss = 0.f;
        #pragma unroll
        for (int i = 0; i < 8; ++i) { float v = sM[r][j + 16 * i]; ss += v * v; }
        #pragma unroll
        for (int m = 1; m < 16; m <<= 1) ss += __shfl_xor(ss, m, 16);
        float sc = 1.0f / fmaxf(sqrtf(ss), 1e-12f);
        #pragma unroll
        for (int i = 0; i < 8; ++i) sM[r][j + 16 * i] *= sc;
        __syncthreads();
        int kt = t >> 6, lane = t & 63;
        int row = lane & 15;
        union { unsigned short u[8]; int4 v; } pk;
        #pragma unroll
        for (int jj = 0; jj < 8; ++jj) {
            int k = kt * 32 + 4 * (lane >> 4) + (jj & 3) + 16 * (jj >> 2);
            pk.u[jj] = f2bf(sM[row][k]);
        }
        reinterpret_cast<int4*>(xfrag)[(size_t)blk * 256 + t] = pk.v;
    } else {
        int c = blk - 64;
        const float4* gw = reinterpret_cast<const float4*>(W + (size_t)c * S * E);
        float4* s4 = reinterpret_cast<float4*>(&sM[0][0]);
        #pragma unroll
        for (int i = 0; i < 4; ++i) s4[t + 256 * i] = gw[t + 256 * i];
        __syncthreads();
        int r = t >> 3, j = t & 7;
        float ss = 0.f;
        #pragma unroll
        for (int i = 0; i < 16; ++i) { float v = sM[r][j + 8 * i]; ss += v * v; }
        #pragma unroll
        for (int m = 1; m < 8; m <<= 1) ss += __shfl_xor(ss, m, 8);
        float sc = 1.0f / fmaxf(sqrtf(ss), 1e-12f);
        #pragma unroll
        for (int i = 0; i < 16; ++i) sM[r][j + 8 * i] *= sc;
        __syncthreads();
        // pack wfrag: chunk ci = (kt, mt, lane); keep a copy in LDS for the Gram
        int4* gwf = reinterpret_cast<int4*>(wfrag) + (size_t)c * 512;
        for (int ci = t; ci < 512; ci += 256) {
            int kt = ci >> 7, mt = (ci >> 6) & 1, lane = ci & 63;
            int s = mt * 16 + (lane & 15);
            union { unsigned short u[8]; int4 v; } pk;
            #pragma unroll
            for (int jj = 0; jj < 8; ++jj) {
                int k = kt * 32 + 4 * (lane >> 4) + (jj & 3) + 16 * (jj >> 2);
                pk.u[jj] = f2bf(sM[s][k]);
            }
            wf[ci] = pk.v;
            gwf[ci] = pk.v;
        }
        __syncthreads();
        // Gram via MFMA: wave w computes D(mt=0..1, nt=w) = sum_kt A(kt,mt)*A(kt,nt)
        int w = t >> 6, lane = t & 63;
        if (w < 2) {
            const bf16x8* f = reinterpret_cast<const bf16x8*>(wf);
            f32x4 d0 = {0.f, 0.f, 0.f, 0.f}, d1 = d0;
            #pragma unroll
            for (int kt = 0; kt < 4; ++kt) {
                bf16x8 bnt = f[kt * 128 + w * 64 + lane];
                bf16x8 a0  = f[kt * 128 + lane];
                bf16x8 a1  = f[kt * 128 + 64 + lane];
                d0 = __builtin_amdgcn_mfma_f32_16x16x32_bf16(a0, bnt, d0, 0, 0, 0);
                d1 = __builtin_amdgcn_mfma_f32_16x16x32_bf16(a1, bnt, d1, 0, 0, 0);
            }
            // gfrag[nt=w].u[r+4*mt] = D(mt,nt)[r]  (via G symmetry)
            union { unsigned short u[8]; int4 v; } pk;
            #pragma unroll
            for (int r2 = 0; r2 < 4; ++r2) {
                pk.u[r2]     = f2bf(d0[r2]);
                pk.u[r2 + 4] = f2bf(d1[r2]);
            }
            reinterpret_cast<int4*>(gfrag)[(size_t)c * 128 + w * 64 + lane] = pk.v;
        }
    }
}

// Fused logits: block = 128 b-rows x 4 classes (wave w = class c0+w).
// GEMM1: coef[s][b] = Wn[c].xn^T (M=32 -> 2 mt, N=128 -> 8 bt, K=128 -> 4 kt)
// GEMM2: H = G.coef; logit = |coef|^2 / max(sqrt(coef.H), 1e-12)
__global__ __launch_bounds__(256) void k_logits_mfma(const unsigned short* __restrict__ xfrag,
                                                     const unsigned short* __restrict__ wfrag,
                                                     const unsigned short* __restrict__ gfrag,
                                                     float* __restrict__ logits) {
    __shared__ int4 smem[4608];  // 72KB: X [0,2048) | W [2048,4096) | G [4096,4608)
    int t = threadIdx.x;
    int w = t >> 6, lane = t & 63;
    int b0 = blockIdx.x * 128;
    int c0 = blockIdx.y * 4;

    const int4* gX = reinterpret_cast<const int4*>(xfrag) + (size_t)(b0 >> 4) * 256;
    const int4* gW = reinterpret_cast<const int4*>(wfrag) + (size_t)c0 * 512;
    const int4* gG = reinterpret_cast<const int4*>(gfrag) + (size_t)c0 * 128;
    #pragma unroll
    for (int i = 0; i < 8; ++i) smem[t + 256 * i] = gX[t + 256 * i];
    #pragma unroll
    for (int i = 0; i < 8; ++i) smem[2048 + t + 256 * i] = gW[t + 256 * i];
    #pragma unroll
    for (int i = 0; i < 2; ++i) smem[4096 + t + 256 * i] = gG[t + 256 * i];
    __syncthreads();

    const bf16x8* fr = reinterpret_cast<const bf16x8*>(smem);
    const bf16x8* fX = fr;                    // [bt][kt][64]
    const bf16x8* fW = fr + 2048 + w * 512;   // [kt][mt][64]
    const bf16x8* fG = fr + 4096 + w * 128;   // [mt][64]

    f32x4 acc[2][8];
    #pragma unroll
    for (int m = 0; m < 2; ++m)
        #pragma unroll
        for (int bt = 0; bt < 8; ++bt) acc[m][bt] = (f32x4){0.f, 0.f, 0.f, 0.f};

    #pragma unroll
    for (int kt = 0; kt < 4; ++kt) {
        bf16x8 a0 = fW[kt * 128 + lane];
        bf16x8 a1 = fW[kt * 128 + 64 + lane];
        #pragma unroll
        for (int bt = 0; bt < 8; ++bt) {
            bf16x8 bv = fX[bt * 256 + kt * 64 + lane];
            acc[0][bt] = __builtin_amdgcn_mfma_f32_16x16x32_bf16(a0, bv, acc[0][bt], 0, 0, 0);
            acc[1][bt] = __builtin_amdgcn_mfma_f32_16x16x32_bf16(a1, bv, acc[1][bt], 0, 0, 0);
        }
    }

    bf16x8 g0 = fG[lane], g1 = fG[64 + lane];
    int c = c0 + w;
    #pragma unroll
    for (int bt = 0; bt < 8; ++bt) {
        union { unsigned short u[8]; bf16x8 v; } p;
        #pragma unroll
        for (int r = 0; r < 4; ++r) {
            p.u[r]     = f2bf(acc[0][bt][r]);
            p.u[r + 4] = f2bf(acc[1][bt][r]);
        }
        f32x4 h0 = {0.f, 0.f, 0.f, 0.f}, h1 = h0;
        h0 = __builtin_amdgcn_mfma_f32_16x16x32_bf16(g0, p.v, h0, 0, 0, 0);
        h1 = __builtin_amdgcn_mfma_f32_16x16x32_bf16(g1, p.v, h1, 0, 0, 0);
        float n = 0.f, q = 0.f;
        #pragma unroll
        for (int r = 0; r < 4; ++r) {
            n += acc[0][bt][r] * acc[0][bt][r] + acc[1][bt][r] * acc[1][bt][r];
            q += acc[0][bt][r] * h0[r] + acc[1][bt][r] * h1[r];
        }
        n += __shfl_xor(n, 16); n += __shfl_xor(n, 32);
        q += __shfl_xor(q, 16); q += __shfl_xor(q, 32);
        if (lane < 16)
            logits[(size_t)(b0 + bt * 16 + lane) * C + c] = n / fmaxf(sqrtf(q), 1e-12f);
    }
}

// Per-row log-softmax + label pick
__global__ void k_loss(const float* __restrict__ logits,
                       const float* __restrict__ y,
                       const float* __restrict__ s_ptr,
                       float* __restrict__ loss) {
    int b = blockIdx.x, t = threadIdx.x;  // 128 threads
    float s = s_ptr[0];
    float4 l4 = reinterpret_cast<const float4*>(logits + (size_t)b * C)[t];
    float4 y4 = reinterpret_cast<const float4*>(y + (size_t)b * C)[t];
    float z0 = l4.x * s, z1 = l4.y * s, z2 = l4.z * s, z3 = l4.w * s;
    float m = fmaxf(fmaxf(z0, z1), fmaxf(z2, z3));
    #pragma unroll
    for (int off = 32; off; off >>= 1) m = fmaxf(m, __shfl_xor(m, off));
    __shared__ float redm[2];
    if ((t & 63) == 0) redm[t >> 6] = m;
    __syncthreads();
    m = fmaxf(redm[0], redm[1]);
    float se = expf(z0 - m) + expf(z1 - m) + expf(z2 - m) + expf(z3 - m);
    float yz = y4.x * z0 + y4.y * z1 + y4.z * z2 + y4.w * z3;
    #pragma unroll
    for (int off = 32; off; off >>= 1) {
        se += __shfl_xor(se, off);
        yz += __shfl_xor(yz, off);
    }
    __shared__ float red2[4];
    if ((t & 63) == 0) { red2[t >> 6] = se; red2[2 + (t >> 6)] = yz; }
    __syncthreads();
    if (t == 0) loss[b] = m + logf(red2[0] + red2[1]) - (red2[2] + red2[3]);
}

__global__ void k_reduce(const float* __restrict__ loss, float* __restrict__ out) {
    int t = threadIdx.x;  // 256
    float v = loss[t] + loss[t + 256] + loss[t + 512] + loss[t + 768];
    #pragma unroll
    for (int off = 32; off; off >>= 1) v += __shfl_xor(v, off);
    __shared__ float r[4];
    if ((t & 63) == 0) r[t >> 6] = v;
    __syncthreads();
    if (t == 0) out[0] = (r[0] + r[1] + r[2] + r[3]) * (1.0f / (float)B);
}

extern "C" void kernel_launch(void* const* d_in, const int* in_sizes, int n_in,
                              void* d_out, int out_size, void* d_ws, size_t ws_size,
                              hipStream_t stream) {
    const float* x = (const float*)d_in[0];
    const float* y = (const float*)d_in[1];
    const float* W = (const float*)d_in[2];
    const float* s = (const float*)d_in[3];
    float* ws = (float*)d_ws;
    float* out = (float*)d_out;

    unsigned short* xfrag = (unsigned short*)(ws + OFF_XFRAG);
    unsigned short* wfrag = (unsigned short*)(ws + OFF_WFRAG);
    unsigned short* gfrag = (unsigned short*)(ws + OFF_GFRAG);
    float* logits = ws + OFF_LOGITS;
    float* loss   = ws + OFF_LOSS;

    k_prep<<<576, 256, 0, stream>>>(x, W, xfrag, wfrag, gfrag);
    k_logits_mfma<<<dim3(B / 128, C / 4), 256, 0, stream>>>(xfrag, wfrag, gfrag, logits);
    k_loss<<<B, 128, 0, stream>>>(logits, y, s, loss);
    k_reduce<<<1, 256, 0, stream>>>(loss, out);
}